// Round 9
// baseline (117.183 us; speedup 1.0000x reference)
//
#include <hip/hip_runtime.h>

typedef unsigned short u16;
typedef unsigned int   u32;
typedef __attribute__((ext_vector_type(8))) short bf8;   // 8 x bf16 (4 VGPRs)
typedef __attribute__((ext_vector_type(4))) float f4;    // 4 x f32 accumulator
typedef __attribute__((ext_vector_type(16))) float f16f; // 16 x f32 accumulator (32x32 MFMA)

#define MFMA(a,b,c)   __builtin_amdgcn_mfma_f32_16x16x32_bf16(a,b,c,0,0,0)
#define MFMA32(a,b,c) __builtin_amdgcn_mfma_f32_32x32x16_bf16(a,b,c,0,0,0)

__device__ __forceinline__ u16 f2bf(float f){
  u32 u = __float_as_uint(f);
  u += 0x7fffu + ((u >> 16) & 1u);          // RNE
  return (u16)(u >> 16);
}
__device__ __forceinline__ float bf2f(u16 h){ return __uint_as_float(((u32)h) << 16); }
__device__ __forceinline__ u32 pk2(float a, float b){ return (u32)f2bf(a) | ((u32)f2bf(b) << 16); }

__device__ __forceinline__ void glds16(const u16* g, u16* l){
  __builtin_amdgcn_global_load_lds((const __attribute__((address_space(1))) u32*)g,
                                   (__attribute__((address_space(3))) u32*)l, 16, 0, 0);
}

// ---- swizzled LDS bf16 matrix helpers (16x16 path) ----
__device__ __forceinline__ bf8 ldsFrag(const char* m, int row0, int k0, int pitch){
  int l = threadIdx.x & 63;
  int r = row0 + (l & 15);
  int kb = ((k0 + ((l >> 4) << 3)) << 1) ^ ((r & 7) << 4);
  return *(const bf8*)(m + r * pitch + kb);
}
__device__ __forceinline__ void ldsPut(char* m, int row, int col, int pitch, u16 v){
  int kb = (col << 1) ^ ((row & 7) << 4);
  *(u16*)(m + row * pitch + kb) = v;
}

// ---- k_ns helpers: pitch-256B rows, chunk swizzle (row&15)<<4 ----
__device__ __forceinline__ bf8 fragNS(const char* m, int r0, int ks, int l){
  int r = r0 + (l & 31);
  int kb = ((ks << 5) + ((l >> 5) << 4)) ^ ((r & 15) << 4);
  return *(const bf8*)(m + r * 256 + kb);
}
__device__ __forceinline__ bf8 fragWT(const char* m, int r0, int ks, int l){
  int r = r0 + (l & 31);
  int kb = ((ks << 5) + ((l >> 5) << 4)) ^ ((r & 15) << 4);
  return *(const bf8*)(m + r * 512 + kb);
}
__device__ __forceinline__ char* nsAddr(char* m, int row, int col4){
  return m + row * 256 + ((col4 << 1) ^ ((row & 15) << 4));
}

// 64x64 matmul pass: acc += A[R0.., :] @ Bsym[C0.., :]^T
__device__ __forceinline__ void mmPass(const char* A, const char* B, f16f (&acc)[2][2],
                                       int R0, int C0, int l){
  #pragma unroll
  for (int ks = 0; ks < 8; ++ks){
    bf8 a0 = fragNS(A, R0,      ks, l);
    bf8 a1 = fragNS(A, R0 + 32, ks, l);
    bf8 b0 = fragNS(B, C0,      ks, l);
    bf8 b1 = fragNS(B, C0 + 32, ks, l);
    acc[0][0] = MFMA32(a0, b0, acc[0][0]); acc[0][1] = MFMA32(a0, b1, acc[0][1]);
    acc[1][0] = MFMA32(a1, b0, acc[1][0]); acc[1][1] = MFMA32(a1, b1, acc[1][1]);
  }
}

// write 64x64 tile transposed (valid by symmetry), vectorized b64 stores.
__device__ __forceinline__ void writeTile(char* D, const f16f (&acc)[2][2], int R0, int C0, int l,
                                          float scale, float dval, const uint2* adv){
  #pragma unroll
  for (int ri = 0; ri < 2; ++ri)
  #pragma unroll
  for (int ci = 0; ci < 2; ++ci)
  #pragma unroll
  for (int g = 0; g < 4; ++g){
    int srow = C0 + ci * 32 + (l & 31);
    int scol = R0 + ri * 32 + g * 8 + ((l >> 5) << 2);
    float v[4];
    #pragma unroll
    for (int q = 0; q < 4; ++q){
      float x = scale * acc[ri][ci][g * 4 + q];
      x += ((scol + q) == srow) ? dval : 0.f;
      v[q] = x;
    }
    if (adv){
      uint2 ad = adv[(ri * 2 + ci) * 4 + g];
      v[0] += 1.5f * bf2f((u16)ad.x);
      v[1] += 1.5f * bf2f((u16)(ad.x >> 16));
      v[2] += 1.5f * bf2f((u16)ad.y);
      v[3] += 1.5f * bf2f((u16)(ad.y >> 16));
    }
    *(uint2*)nsAddr(D, srow, scol) = make_uint2(pk2(v[0], v[1]), pk2(v[2], v[3]));
  }
}

// =====================================================================
// K_prep: zero logits + convert w_dr -> bf16 pre-swizzled per-chunk LDS image
// =====================================================================
__global__ __launch_bounds__(256) void k_prep(const float* __restrict__ wdr,
                                              float* __restrict__ logits,
                                              u16* __restrict__ prep){
  int i = blockIdx.x * 256 + threadIdx.x;   // grid 256 -> 65536 threads
  if (i < 16384) logits[i] = 0.f;
  #pragma unroll
  for (int j = 0; j < 2; ++j){
    int e = i + j * 65536;
    int chunk = e >> 13, rem = e & 8191, d = rem >> 6, cb2 = rem & 63;
    int c = ((cb2 * 2) ^ ((d & 7) << 4)) >> 1;
    prep[e] = f2bf(wdr[d * 1024 + chunk * 64 + c]);
  }
}

// =====================================================================
// K1: 1x1 conv GEMM + BN1 + ReLU, center over d, scale 1/sqrt(128),
//     write W [b][hw][d] and WT [b][d][hw] (bf16)
// =====================================================================
__global__ __launch_bounds__(512) void k_conv(
    const u16* __restrict__ wprep, const float* __restrict__ x, const float* __restrict__ bdr,
    const float* __restrict__ g1, const float* __restrict__ be1,
    const float* __restrict__ m1, const float* __restrict__ v1,
    u16* __restrict__ Wg, u16* __restrict__ WTg){
  __shared__ union {
    struct { u16 A[4][8192]; u16 Bt[2][2048]; } s;   // 72KB -> 2 blocks/CU
    struct { float y[128 * 33]; float musum[512]; float mu[32]; } e;
  } sm;
  int t = threadIdx.x;
  int b = blockIdx.x >> 3, hw0 = (blockIdx.x & 7) * 32;
  const float* xb = x + (size_t)b * 262144 + hw0;

  int w = t >> 6, l = t & 63;
  int d0 = (w >> 1) * 32, hh = (w & 1) * 16;
  int lc = l & 15, lr = (l >> 4) * 4;

  const f4 fz = {0.f, 0.f, 0.f, 0.f};
  f4 acc[2]; acc[0] = fz; acc[1] = fz;

  int cp = t >> 5, hwl = t & 31;
  int bo0 = (4 * cp) ^ ((hwl & 7) << 4);
  int bo1 = (4 * cp + 64) ^ ((hwl & 7) << 4);

  float br[3][4];
  #pragma unroll
  for (int j = 0; j < 3; ++j){
    glds16(wprep + j * 8192 + t * 8,        sm.s.A[j] + t * 8);
    glds16(wprep + j * 8192 + 4096 + t * 8, sm.s.A[j] + 4096 + t * 8);
    __builtin_amdgcn_sched_barrier(0);
    int c0 = j * 64;
    br[j][0] = xb[(size_t)(c0 + 2 * cp)      * 256 + hwl];
    br[j][1] = xb[(size_t)(c0 + 2 * cp + 1)  * 256 + hwl];
    br[j][2] = xb[(size_t)(c0 + 2 * cp + 32) * 256 + hwl];
    br[j][3] = xb[(size_t)(c0 + 2 * cp + 33) * 256 + hwl];
    __builtin_amdgcn_sched_barrier(0);
  }

  #pragma unroll
  for (int k = 0; k < 16; ++k){
    if (k <= 12){
      const u16* src = wprep + (k + 3) * 8192;
      glds16(src + t * 8,        sm.s.A[(k + 3) & 3] + t * 8);
      glds16(src + 4096 + t * 8, sm.s.A[(k + 3) & 3] + 4096 + t * 8);
    }
    __builtin_amdgcn_sched_barrier(0);
    if (k <= 12)      asm volatile("s_waitcnt vmcnt(14)" ::: "memory");
    else if (k == 13) asm volatile("s_waitcnt vmcnt(12)" ::: "memory");
    else if (k == 14) asm volatile("s_waitcnt vmcnt(6)" ::: "memory");
    else              asm volatile("s_waitcnt vmcnt(0)" ::: "memory");
    __builtin_amdgcn_sched_barrier(0);
    *(u32*)((char*)sm.s.Bt[k & 1] + hwl * 128 + bo0) = pk2(br[k % 3][0], br[k % 3][1]);
    *(u32*)((char*)sm.s.Bt[k & 1] + hwl * 128 + bo1) = pk2(br[k % 3][2], br[k % 3][3]);
    __builtin_amdgcn_sched_barrier(0);
    if (k <= 12){
      int c0 = (k + 3) * 64;
      br[k % 3][0] = xb[(size_t)(c0 + 2 * cp)      * 256 + hwl];
      br[k % 3][1] = xb[(size_t)(c0 + 2 * cp + 1)  * 256 + hwl];
      br[k % 3][2] = xb[(size_t)(c0 + 2 * cp + 32) * 256 + hwl];
      br[k % 3][3] = xb[(size_t)(c0 + 2 * cp + 33) * 256 + hwl];
    }
    __builtin_amdgcn_sched_barrier(0);
    asm volatile("s_waitcnt lgkmcnt(0)" ::: "memory");
    __builtin_amdgcn_sched_barrier(0);
    __builtin_amdgcn_s_barrier();
    __builtin_amdgcn_sched_barrier(0);
    #pragma unroll
    for (int ks = 0; ks < 2; ++ks){
      int k0 = ks * 32;
      bf8 a0 = ldsFrag((const char*)sm.s.A[k & 3], d0,      k0, 128);
      bf8 a1 = ldsFrag((const char*)sm.s.A[k & 3], d0 + 16, k0, 128);
      bf8 b0 = ldsFrag((const char*)sm.s.Bt[k & 1], hh, k0, 128);
      acc[0] = MFMA(a0, b0, acc[0]);
      acc[1] = MFMA(a1, b0, acc[1]);
    }
    __builtin_amdgcn_sched_barrier(0);
    __builtin_amdgcn_s_barrier();
    __builtin_amdgcn_sched_barrier(0);
  }
  __syncthreads();

  #pragma unroll
  for (int i = 0; i < 2; ++i)
    #pragma unroll
    for (int r = 0; r < 4; ++r){
      int d = d0 + i * 16 + lr + r;
      float s1 = g1[d] * rsqrtf(v1[d] + 1e-5f);
      float t1 = (bdr[d] - m1[d]) * s1 + be1[d];
      int hwp = hh + lc;
      sm.e.y[d * 33 + hwp] = fmaxf(acc[i][r] * s1 + t1, 0.f);
    }
  __syncthreads();
  { int part = t >> 5, col = t & 31;
    float s = 0.f;
    #pragma unroll
    for (int i2 = 0; i2 < 8; ++i2) s += sm.e.y[(part * 8 + i2) * 33 + col];
    sm.e.musum[part * 32 + col] = s;
  }
  __syncthreads();
  if (t < 32){
    float m = 0.f;
    #pragma unroll
    for (int p = 0; p < 16; ++p) m += sm.e.musum[p * 32 + t];
    sm.e.mu[t] = m * (1.0f / 128.0f);
  }
  __syncthreads();
  const float ISM = 0.08838834764831845f;   // 1/sqrt(128)
  { int hwp = t >> 4, dc = (t & 15) * 8;
    float muv = sm.e.mu[hwp];
    u32 q[4];
    #pragma unroll
    for (int jj = 0; jj < 4; ++jj){
      float a = (sm.e.y[(dc + 2 * jj)     * 33 + hwp] - muv) * ISM;
      float c = (sm.e.y[(dc + 2 * jj + 1) * 33 + hwp] - muv) * ISM;
      q[jj] = pk2(a, c);
    }
    *(uint4*)(Wg + ((size_t)(b * 256 + hw0 + hwp) * 128 + dc)) = make_uint4(q[0], q[1], q[2], q[3]);
  }
  { int d = t >> 2, hc = (t & 3) * 8;
    u32 q[4];
    #pragma unroll
    for (int jj = 0; jj < 4; ++jj){
      int h0 = hc + 2 * jj, h1 = hc + 2 * jj + 1;
      float a = (sm.e.y[d * 33 + h0] - sm.e.mu[h0]) * ISM;
      float c = (sm.e.y[d * 33 + h1] - sm.e.mu[h1]) * ISM;
      q[jj] = pk2(a, c);
    }
    *(uint4*)(WTg + ((size_t)(b * 128 + d) * 256 + hw0 + hc)) = make_uint4(q[0], q[1], q[2], q[3]);
  }
}

// =====================================================================
// K3: per-batch Gram + Newton-Schulz (3 passes/iter, G register-resident,
//     32x32x16 MFMA, 64x64 tiles, b64 epilogues; pass2 split across 8 waves)
// =====================================================================
extern __shared__ char smns[];
__global__ __launch_bounds__(512, 2) void k_ns(const u16* __restrict__ WT,
                                               u16* __restrict__ yf, float* __restrict__ normAg){
  int b = blockIdx.x, t = threadIdx.x;
  char* Yb = smns;
  char* Zb = smns + 32768;
  char* T1 = smns + 65536;
  char* T2 = smns + 98304;
  char* T3 = smns + 131072;
  char* WTl = smns + 65536;
  char* G   = T3;
  float* trp = (float*)smns;

  int w = t >> 6, l = t & 63;
  int wq = w & 3;
  int R0 = (wq >> 1) * 64, C0 = (wq & 1) * 64;

  { const u16* src = WT + (size_t)b * 32768;
    int row = t >> 2, q = t & 3;
    #pragma unroll
    for (int j = 0; j < 8; ++j) {
      int c16 = q + j * 4;
      bf8 v = *(const bf8*)(src + row * 256 + c16 * 8);
      int ph = c16 ^ (row & 15);
      *(bf8*)(WTl + row * 512 + ph * 16) = v;
    }
  }
  if (t == 0) *trp = 0.f;
  __syncthreads();

  int R0g = (w & 3) * 32, C0g = (w >> 2) * 64;
  const f16f fz16 = {};
  f16f gac[2]; gac[0] = fz16; gac[1] = fz16;
  #pragma unroll
  for (int ks = 0; ks < 16; ++ks){
    bf8 a  = fragWT(WTl, R0g,      ks, l);
    bf8 b0 = fragWT(WTl, C0g,      ks, l);
    bf8 b1 = fragWT(WTl, C0g + 32, ks, l);
    gac[0] = MFMA32(a, b0, gac[0]);
    gac[1] = MFMA32(a, b1, gac[1]);
  }
  float tp = 0.f;
  #pragma unroll
  for (int ci = 0; ci < 2; ++ci)
    #pragma unroll
    for (int e = 0; e < 16; ++e){
      int row = R0g + (e & 3) + 8 * (e >> 2) + ((l >> 5) << 2);
      int col = C0g + ci * 32 + (l & 31);
      if (row == col) tp += gac[ci][e];
    }
  #pragma unroll
  for (int off = 32; off > 0; off >>= 1) tp += __shfl_down(tp, off);
  if (l == 0) atomicAdd(trp, tp);
  __syncthreads();

  float normA = fmaxf(*trp / 3.0f, 1e-12f);
  if (t == 0) normAg[b] = normA;
  float inv = 1.0f / normA;
  #pragma unroll
  for (int ci = 0; ci < 2; ++ci)
    #pragma unroll
    for (int g = 0; g < 4; ++g){
      int srow = C0g + ci * 32 + (l & 31);
      int scol = R0g + g * 8 + ((l >> 5) << 2);
      float v0 = gac[ci][g * 4 + 0] * inv, v1 = gac[ci][g * 4 + 1] * inv;
      float v2 = gac[ci][g * 4 + 2] * inv, v3 = gac[ci][g * 4 + 3] * inv;
      *(uint2*)nsAddr(G, srow, scol) = make_uint2(pk2(v0, v1), pk2(v2, v3));
    }
  __syncthreads();

  bf8 gA[8], gB[8];
  #pragma unroll
  for (int ks = 0; ks < 8; ++ks){
    gA[ks] = fragNS(G, C0,      ks, l);
    gB[ks] = fragNS(G, C0 + 32, ks, l);
  }
  { int row = t >> 2, q4 = t & 3;
    #pragma unroll
    for (int j = 0; j < 4; ++j){
      int c16 = q4 * 4 + j;
      int ph = c16 ^ (row & 15);
      bf8 gg = *(const bf8*)(G + row * 256 + ph * 16);
      bf8 yv, zv;
      #pragma unroll
      for (int e = 0; e < 8; ++e){
        int col = c16 * 8 + e;
        float y = -0.5f * bf2f((u16)gg[e]) + ((col == row) ? 1.5f : 0.f);
        yv[e] = (short)f2bf(y);
        zv[e] = (col == row) ? (short)f2bf(-0.5f) : (short)0;
      }
      *(bf8*)(Yb + row * 256 + ph * 16) = yv;
      *(bf8*)(Zb + row * 256 + ph * 16) = zv;
    }
  }
  __syncthreads();

  float z0 = 1.5f;
  for (int it = 0; it < 4; ++it){
    {
      f16f acc[2][2]; acc[0][0] = fz16; acc[0][1] = fz16; acc[1][0] = fz16; acc[1][1] = fz16;
      const char* As = (w < 4) ? Zb : Yb;
      #pragma unroll
      for (int ks = 0; ks < 8; ++ks){
        bf8 a0 = fragNS(As, R0,      ks, l);
        bf8 a1 = fragNS(As, R0 + 32, ks, l);
        acc[0][0] = MFMA32(a0, gA[ks], acc[0][0]); acc[0][1] = MFMA32(a0, gB[ks], acc[0][1]);
        acc[1][0] = MFMA32(a1, gA[ks], acc[1][0]); acc[1][1] = MFMA32(a1, gB[ks], acc[1][1]);
      }
      writeTile((w < 4) ? T1 : T3, acc, R0, C0, l, 1.0f, (w < 4) ? z0 : 0.f, nullptr);
    }
    __syncthreads();

    uint2 adv[16];
    {
      const char* addsrc = (w < 4) ? Zb : Yb;
      #pragma unroll
      for (int ri = 0; ri < 2; ++ri)
      #pragma unroll
      for (int ci = 0; ci < 2; ++ci)
      #pragma unroll
      for (int g = 0; g < 4; ++g){
        int srow = C0 + ci * 32 + (l & 31);
        int scol = R0 + ri * 32 + g * 8 + ((l >> 5) << 2);
        adv[(ri * 2 + ci) * 4 + g] = *(const uint2*)nsAddr((char*)addsrc, srow, scol);
      }
      int hC0 = C0 + ((w >> 2) << 5);           // 32-col half per wave
      f16f a2[2]; a2[0] = fz16; a2[1] = fz16;
      #pragma unroll
      for (int ks = 0; ks < 8; ++ks){
        bf8 a0 = fragNS(T1, R0,      ks, l);
        bf8 a1 = fragNS(T1, R0 + 32, ks, l);
        bf8 b0 = fragNS(Yb, hC0,     ks, l);
        a2[0] = MFMA32(a0, b0, a2[0]);
        a2[1] = MFMA32(a1, b0, a2[1]);
      }
      #pragma unroll
      for (int ri = 0; ri < 2; ++ri)
      #pragma unroll
      for (int g = 0; g < 4; ++g){
        int srow = hC0 + (l & 31);
        int scol = R0 + ri * 32 + g * 8 + ((l >> 5) << 2);
        float v0 = -0.5f * a2[ri][g * 4 + 0], v1 = -0.5f * a2[ri][g * 4 + 1];
        float v2 = -0.5f * a2[ri][g * 4 + 2], v3 = -0.5f * a2[ri][g * 4 + 3];
        *(uint2*)nsAddr(T2, srow, scol) = make_uint2(pk2(v0, v1), pk2(v2, v3));
      }
    }
    __syncthreads();

    if ((w >= 4) || (it < 3)){
      f16f acc[2][2]; acc[0][0] = fz16; acc[0][1] = fz16; acc[1][0] = fz16; acc[1][1] = fz16;
      const char* A3 = (w < 4) ? T2 : T3;
      const char* B3 = (w < 4) ? T1 : T2;
      mmPass(A3, B3, acc, R0, C0, l);
      writeTile((w < 4) ? Zb : Yb, acc, R0, C0, l, 1.0f, 0.f, adv);
    }
    __syncthreads();
    z0 *= 1.5f;
  }

  { int row = t >> 2, q = t & 3;
    u16* dst = yf + (size_t)b * 16384 + row * 128;
    #pragma unroll
    for (int j = 0; j < 4; ++j) {
      int c16 = q * 4 + j;
      int ph = c16 ^ (row & 15);
      *(bf8*)(dst + c16 * 8) = *(const bf8*)(Yb + row * 256 + ph * 16);
    }
  }
}

// =====================================================================
// K4: S = W @ yf @ W^T / sqrt(normA), then BN2 row-affine + rc -> s_post bf16
// =====================================================================
extern __shared__ char smex[];
__global__ __launch_bounds__(512) void k_expand(
    const u16* __restrict__ Wg, const u16* __restrict__ yf, const float* __restrict__ normAg,
    const float* __restrict__ g2, const float* __restrict__ be2, const float* __restrict__ m2,
    const float* __restrict__ v2, const float* __restrict__ rcw, const float* __restrict__ rcb,
    u16* __restrict__ sp){
  int blk = blockIdx.x, b = blk >> 2, iband = blk & 3;
  char* Bm = smex;
  char* Yl = smex + 65536;
  char* El = smex + 98304;
  int t = threadIdx.x;
  { const u16* src = Wg + (size_t)b * 32768;
    int row = t >> 1, q = t & 1;
    #pragma unroll
    for (int j = 0; j < 8; ++j) {
      int c16 = q + j * 2;
      bf8 v = *(const bf8*)(src + row * 128 + c16 * 8);
      int ph = c16 ^ (row & 7);
      *(bf8*)(Bm + row * 256 + ph * 16) = v;
    } }
  { const u16* src = yf + (size_t)b * 16384;
    int row = t >> 2, q = t & 3;
    #pragma unroll
    for (int j = 0; j < 4; ++j) {
      int c16 = q + j * 4;
      bf8 v = *(const bf8*)(src + row * 128 + c16 * 8);
      int ph = c16 ^ (row & 7);
      *(bf8*)(Yl + row * 256 + ph * 16) = v;
    } }
  __syncthreads();
  int w = t >> 6, l = t & 63, lc = l & 15, lr = (l >> 4) * 4;
  const f4 fz = {0.f, 0.f, 0.f, 0.f};
  { int r0 = (w >> 2) * 32, c0 = (w & 3) * 32;
    f4 acc[2][2];
    acc[0][0] = fz; acc[0][1] = fz; acc[1][0] = fz; acc[1][1] = fz;
    #pragma unroll
    for (int kk = 0; kk < 4; ++kk) {
      int k0 = kk * 32;
      bf8 a0 = ldsFrag(Bm, iband * 64 + r0,      k0, 256);
      bf8 a1 = ldsFrag(Bm, iband * 64 + r0 + 16, k0, 256);
      bf8 b0 = ldsFrag(Yl, c0,      k0, 256);
      bf8 b1 = ldsFrag(Yl, c0 + 16, k0, 256);
      acc[0][0] = MFMA(a0, b0, acc[0][0]); acc[0][1] = MFMA(a0, b1, acc[0][1]);
      acc[1][0] = MFMA(a1, b0, acc[1][0]); acc[1][1] = MFMA(a1, b1, acc[1][1]);
    }
    #pragma unroll
    for (int i = 0; i < 2; ++i)
      #pragma unroll
      for (int j = 0; j < 2; ++j)
        #pragma unroll
        for (int r = 0; r < 4; ++r)
          ldsPut(El, r0 + i * 16 + lr + r, c0 + j * 16 + lc, 256, f2bf(acc[i][j][r]));
  }
  __syncthreads();
  { float invs = rsqrtf(normAg[b]);
    int r0 = (w >> 2) * 32, c0 = (w & 3) * 64;
    f4 acc[2][4];
    #pragma unroll
    for (int i = 0; i < 2; ++i)
      #pragma unroll
      for (int j = 0; j < 4; ++j) acc[i][j] = fz;
    #pragma unroll
    for (int kk = 0; kk < 4; ++kk) {
      int k0 = kk * 32;
      bf8 a0 = ldsFrag(El, r0,      k0, 256);
      bf8 a1 = ldsFrag(El, r0 + 16, k0, 256);
      bf8 b0 = ldsFrag(Bm, c0,      k0, 256);
      bf8 b1 = ldsFrag(Bm, c0 + 16, k0, 256);
      bf8 b2 = ldsFrag(Bm, c0 + 32, k0, 256);
      bf8 b3 = ldsFrag(Bm, c0 + 48, k0, 256);
      acc[0][0] = MFMA(a0, b0, acc[0][0]); acc[0][1] = MFMA(a0, b1, acc[0][1]);
      acc[0][2] = MFMA(a0, b2, acc[0][2]); acc[0][3] = MFMA(a0, b3, acc[0][3]);
      acc[1][0] = MFMA(a1, b0, acc[1][0]); acc[1][1] = MFMA(a1, b1, acc[1][1]);
      acc[1][2] = MFMA(a1, b2, acc[1][2]); acc[1][3] = MFMA(a1, b3, acc[1][3]);
    }
    #pragma unroll
    for (int i = 0; i < 2; ++i)
      #pragma unroll
      for (int r = 0; r < 4; ++r) {
        int il = r0 + i * 16 + lr + r;
        int ig = iband * 64 + il;
        float bs = g2[ig] * rsqrtf(v2[ig] + 1e-5f);
        float al = bs * rcw[ig];
        float be = (be2[ig] - m2[ig] * bs) * rcw[ig] + rcb[ig];
        #pragma unroll
        for (int j = 0; j < 4; ++j) {
          int jg = c0 + j * 16 + lc;
          sp[(size_t)b * 65536 + ig * 256 + jg] = f2bf(acc[i][j][r] * invs * al + be);
        }
      }
  }
}

// =====================================================================
// K5: high-occupancy split-K GEMM; launch_bounds(256,5) -> ~100 VGPR so all
// 16 loads/thread stay in flight (MLP); fragment-linear float4 partial stores.
// grid 2048 = 512 kc (K=128) x 4 rq.
// partial4 layout (per kc, 4096 float4): c4 = rq*1024 + t*4 + (g*2+j), elems = q.
// =====================================================================
__global__ __launch_bounds__(256, 5) void k_fc(const u16* __restrict__ sp,
                                               const float* __restrict__ fcw,
                                               float4* __restrict__ partial4){
  __shared__ char Bl[16384];   // [64 r][128 k] bf16, swizzled, pitch 256B
  int kc = blockIdx.x >> 2, rq = blockIdx.x & 3;
  int t = threadIdx.x, w = t >> 6, l = t & 63;
  int k0 = kc * 128, rbase = rq * 64;
  int br0 = (w & 1) * 32;      // batch rows (A/M)
  int cr0 = (w >> 1) * 32;     // fcw rows  (B/N)

  // B: 8 coalesced float4/thread (fcw row = 32 float4)
  float4 fb[8];
  #pragma unroll
  for (int j = 0; j < 8; ++j){
    int fid = t + 256 * j;            // 0..2047
    int row = fid >> 5, c4 = fid & 31;
    fb[j] = *(const float4*)(fcw + (size_t)(rbase + row) * 65536 + k0 + c4 * 4);
  }
  // A: 8 bf8 fragment gathers from sp (L2/L3-resident)
  bf8 fa[8];
  #pragma unroll
  for (int g = 0; g < 2; ++g)
    #pragma unroll
    for (int ks = 0; ks < 4; ++ks)
      fa[g * 4 + ks] = *(const bf8*)(sp + (size_t)(br0 + 16 * g + (l & 15)) * 65536
                                     + k0 + ks * 32 + (l >> 4) * 8);
  // write B -> LDS swizzled
  #pragma unroll
  for (int j = 0; j < 8; ++j){
    int fid = t + 256 * j;
    int row = fid >> 5, c4 = fid & 31;
    int off = row * 256 + ((c4 * 8) ^ ((row & 7) << 4));
    *(uint2*)(Bl + off) = make_uint2(pk2(fb[j].x, fb[j].y), pk2(fb[j].z, fb[j].w));
  }
  __syncthreads();

  const f4 fz = {0.f, 0.f, 0.f, 0.f};
  f4 acc[2][2];
  acc[0][0] = fz; acc[0][1] = fz; acc[1][0] = fz; acc[1][1] = fz;
  #pragma unroll
  for (int ks = 0; ks < 4; ++ks){
    bf8 b0 = ldsFrag(Bl, cr0,      ks * 32, 256);
    bf8 b1 = ldsFrag(Bl, cr0 + 16, ks * 32, 256);
    acc[0][0] = MFMA(fa[ks],     b0, acc[0][0]);
    acc[0][1] = MFMA(fa[ks],     b1, acc[0][1]);
    acc[1][0] = MFMA(fa[4 + ks], b0, acc[1][0]);
    acc[1][1] = MFMA(fa[4 + ks], b1, acc[1][1]);
  }

  // fragment-linear store: contiguous 16 KB per block
  float4* pout = partial4 + (size_t)kc * 4096 + (size_t)(rq * 256 + t) * 4;
  #pragma unroll
  for (int g = 0; g < 2; ++g)
    #pragma unroll
    for (int j = 0; j < 2; ++j){
      f4 v = acc[g][j];
      pout[g * 2 + j] = make_float4(v[0], v[1], v[2], v[3]);
    }
}

// =====================================================================
// K6a: strip-sum partial over kc: p3[s][c4] = sum_{kc ≡ s mod 16} partial4[kc][c4]
// 256 blocks x 256 thr; fully coalesced float4.
// =====================================================================
__global__ __launch_bounds__(256) void k_red1(const float4* __restrict__ partial4,
                                              float4* __restrict__ p3){
  int b = blockIdx.x, t = threadIdx.x;
  int s = b >> 4;                         // 0..15
  int c4 = ((b & 15) << 8) + t;           // 0..4095
  float4 a0 = {0,0,0,0}, a1 = {0,0,0,0}, a2 = {0,0,0,0}, a3 = {0,0,0,0};
  #pragma unroll 2
  for (int j = 0; j < 32; j += 4){
    float4 v0 = partial4[(size_t)(s + (j + 0) * 16) * 4096 + c4];
    float4 v1 = partial4[(size_t)(s + (j + 1) * 16) * 4096 + c4];
    float4 v2 = partial4[(size_t)(s + (j + 2) * 16) * 4096 + c4];
    float4 v3 = partial4[(size_t)(s + (j + 3) * 16) * 4096 + c4];
    a0.x += v0.x; a0.y += v0.y; a0.z += v0.z; a0.w += v0.w;
    a1.x += v1.x; a1.y += v1.y; a1.z += v1.z; a1.w += v1.w;
    a2.x += v2.x; a2.y += v2.y; a2.z += v2.z; a2.w += v2.w;
    a3.x += v3.x; a3.y += v3.y; a3.z += v3.z; a3.w += v3.w;
  }
  float4 s4;
  s4.x = (a0.x + a1.x) + (a2.x + a3.x);
  s4.y = (a0.y + a1.y) + (a2.y + a3.y);
  s4.z = (a0.z + a1.z) + (a2.z + a3.z);
  s4.w = (a0.w + a1.w) + (a2.w + a3.w);
  p3[(size_t)s * 4096 + c4] = s4;
}

// =====================================================================
// K6b: final sum + inverse fragment-permutation scatter to logits
// 16 blocks x 256 thr.
// =====================================================================
__global__ __launch_bounds__(256) void k_red2(const float4* __restrict__ p3,
                                              float* __restrict__ logits){
  int c4 = blockIdx.x * 256 + threadIdx.x;   // 0..4095
  float4 a = {0,0,0,0};
  #pragma unroll
  for (int s = 0; s < 16; ++s){
    float4 v = p3[(size_t)s * 4096 + c4];
    a.x += v.x; a.y += v.y; a.z += v.z; a.w += v.w;
  }
  int rq = c4 >> 10, t = (c4 >> 2) & 255, gj = c4 & 3;
  int g = gj >> 1, j = gj & 1, w = t >> 6, l = t & 63;
  int brow0 = (w & 1) * 32 + g * 16 + ((l >> 4) << 2);
  int rcol  = rq * 64 + (w >> 1) * 32 + j * 16 + (l & 15);
  float* dst = logits + brow0 * 256 + rcol;
  dst[0]   = a.x;
  dst[256] = a.y;
  dst[512] = a.z;
  dst[768] = a.w;
}

// =====================================================================
// K7: out = x * sigmoid(logits + fc_b)
// =====================================================================
__global__ __launch_bounds__(256) void k_mul(const float* __restrict__ x,
                                             const float* __restrict__ logits,
                                             const float* __restrict__ fcb,
                                             float* __restrict__ out, int n4){
  int i = blockIdx.x * 256 + threadIdx.x;
  int str = gridDim.x * 256;
  for (; i < n4; i += str) {
    int e = i << 2;
    int b = e >> 18;
    int hw = e & 255;
    float4 xv = ((const float4*)x)[i];
    float4 lg = *(const float4*)(logits + (b << 8) + hw);
    float4 fb = *(const float4*)(fcb + hw);
    float4 o;
    o.x = xv.x / (1.f + expf(-(lg.x + fb.x)));
    o.y = xv.y / (1.f + expf(-(lg.y + fb.y)));
    o.z = xv.z / (1.f + expf(-(lg.z + fb.z)));
    o.w = xv.w / (1.f + expf(-(lg.w + fb.w)));
    ((float4*)out)[i] = o;
  }
}

// =====================================================================
extern "C" void kernel_launch(void* const* d_in, const int* in_sizes, int n_in,
                              void* d_out, int out_size, void* d_ws, size_t ws_size,
                              hipStream_t stream){
  const float* x   = (const float*)d_in[0];
  const float* wdr = (const float*)d_in[1];
  const float* bdr = (const float*)d_in[2];
  const float* g1  = (const float*)d_in[3];
  const float* be1 = (const float*)d_in[4];
  const float* m1  = (const float*)d_in[5];
  const float* v1  = (const float*)d_in[6];
  const float* g2  = (const float*)d_in[7];
  const float* be2 = (const float*)d_in[8];
  const float* m2  = (const float*)d_in[9];
  const float* v2  = (const float*)d_in[10];
  const float* rcw = (const float*)d_in[11];
  const float* rcb = (const float*)d_in[12];
  const float* fcw = (const float*)d_in[13];
  const float* fcb = (const float*)d_in[14];
  float* out = (float*)d_out;
  char* ws = (char*)d_ws;
  u16*    Wg  = (u16*)(ws);                          // 4 MB
  u16*    WTg = (u16*)(ws + (4u  << 20));            // 4 MB
  u16*    yfg = (u16*)(ws + (8u  << 20));            // 2 MB
  float*  nAg = (float*)(ws + (10u << 20));          // 256 B
  u16*    wpr = (u16*)(ws + (10u << 20) + 4096);     // 256 KB
  u16*    spg = (u16*)(ws + (11u << 20));            // 8 MB
  float*  lgt = (float*)(ws + (20u << 20));          // 64 KB
  float4* p3  = (float4*)(ws + (22u << 20));         // 1 MB  [16][4096] f4
  float4* prt = (float4*)(ws + (24u << 20));         // 33.5 MB [512][4096] f4

  hipFuncSetAttribute((const void*)k_ns,     hipFuncAttributeMaxDynamicSharedMemorySize, 163840);
  hipFuncSetAttribute((const void*)k_expand, hipFuncAttributeMaxDynamicSharedMemorySize, 114688);

  k_prep  <<<256,  256, 0,      stream>>>(wdr, lgt, wpr);
  k_conv  <<<512,  512, 0,      stream>>>(wpr, x, bdr, g1, be1, m1, v1, Wg, WTg);
  k_ns    <<<64,   512, 163840, stream>>>(WTg, yfg, nAg);
  k_expand<<<256,  512, 114688, stream>>>(Wg, yfg, nAg, g2, be2, m2, v2, rcw, rcb, spg);
  k_fc    <<<2048, 256, 0,      stream>>>(spg, fcw, prt);
  k_red1  <<<256,  256, 0,      stream>>>(prt, p3);
  k_red2  <<<16,   256, 0,      stream>>>(p3, lgt);
  k_mul   <<<2048, 256, 0,      stream>>>(x, lgt, fcb, out, 4194304);
}

// Round 10
// 113.881 us; speedup vs baseline: 1.0290x; 1.0290x over previous
//
#include <hip/hip_runtime.h>

typedef unsigned short u16;
typedef unsigned int   u32;
typedef __attribute__((ext_vector_type(8))) short bf8;   // 8 x bf16 (4 VGPRs)
typedef __attribute__((ext_vector_type(4))) float f4;    // 4 x f32 accumulator
typedef __attribute__((ext_vector_type(16))) float f16f; // 16 x f32 accumulator (32x32 MFMA)

#define MFMA(a,b,c)   __builtin_amdgcn_mfma_f32_16x16x32_bf16(a,b,c,0,0,0)
#define MFMA32(a,b,c) __builtin_amdgcn_mfma_f32_32x32x16_bf16(a,b,c,0,0,0)

__device__ __forceinline__ u16 f2bf(float f){
  u32 u = __float_as_uint(f);
  u += 0x7fffu + ((u >> 16) & 1u);          // RNE
  return (u16)(u >> 16);
}
__device__ __forceinline__ float bf2f(u16 h){ return __uint_as_float(((u32)h) << 16); }
__device__ __forceinline__ u32 pk2(float a, float b){ return (u32)f2bf(a) | ((u32)f2bf(b) << 16); }

__device__ __forceinline__ void glds16(const u16* g, u16* l){
  __builtin_amdgcn_global_load_lds((const __attribute__((address_space(1))) u32*)g,
                                   (__attribute__((address_space(3))) u32*)l, 16, 0, 0);
}

// ---- swizzled LDS bf16 matrix helpers (16x16 path) ----
__device__ __forceinline__ bf8 ldsFrag(const char* m, int row0, int k0, int pitch){
  int l = threadIdx.x & 63;
  int r = row0 + (l & 15);
  int kb = ((k0 + ((l >> 4) << 3)) << 1) ^ ((r & 7) << 4);
  return *(const bf8*)(m + r * pitch + kb);
}
__device__ __forceinline__ void ldsPut(char* m, int row, int col, int pitch, u16 v){
  int kb = (col << 1) ^ ((row & 7) << 4);
  *(u16*)(m + row * pitch + kb) = v;
}

// ---- k_ns helpers: pitch-256B rows, chunk swizzle (row&15)<<4 ----
__device__ __forceinline__ bf8 fragNS(const char* m, int r0, int ks, int l){
  int r = r0 + (l & 31);
  int kb = ((ks << 5) + ((l >> 5) << 4)) ^ ((r & 15) << 4);
  return *(const bf8*)(m + r * 256 + kb);
}
__device__ __forceinline__ bf8 fragWT(const char* m, int r0, int ks, int l){
  int r = r0 + (l & 31);
  int kb = ((ks << 5) + ((l >> 5) << 4)) ^ ((r & 15) << 4);
  return *(const bf8*)(m + r * 512 + kb);
}
__device__ __forceinline__ char* nsAddr(char* m, int row, int col4){
  return m + row * 256 + ((col4 << 1) ^ ((row & 15) << 4));
}

// 64x64 matmul pass: acc += A[R0.., :] @ Bsym[C0.., :]^T
__device__ __forceinline__ void mmPass(const char* A, const char* B, f16f (&acc)[2][2],
                                       int R0, int C0, int l){
  #pragma unroll
  for (int ks = 0; ks < 8; ++ks){
    bf8 a0 = fragNS(A, R0,      ks, l);
    bf8 a1 = fragNS(A, R0 + 32, ks, l);
    bf8 b0 = fragNS(B, C0,      ks, l);
    bf8 b1 = fragNS(B, C0 + 32, ks, l);
    acc[0][0] = MFMA32(a0, b0, acc[0][0]); acc[0][1] = MFMA32(a0, b1, acc[0][1]);
    acc[1][0] = MFMA32(a1, b0, acc[1][0]); acc[1][1] = MFMA32(a1, b1, acc[1][1]);
  }
}

// write 64x64 tile transposed (valid by symmetry), vectorized b64 stores.
__device__ __forceinline__ void writeTile(char* D, const f16f (&acc)[2][2], int R0, int C0, int l,
                                          float scale, float dval, const uint2* adv){
  #pragma unroll
  for (int ri = 0; ri < 2; ++ri)
  #pragma unroll
  for (int ci = 0; ci < 2; ++ci)
  #pragma unroll
  for (int g = 0; g < 4; ++g){
    int srow = C0 + ci * 32 + (l & 31);
    int scol = R0 + ri * 32 + g * 8 + ((l >> 5) << 2);
    float v[4];
    #pragma unroll
    for (int q = 0; q < 4; ++q){
      float x = scale * acc[ri][ci][g * 4 + q];
      x += ((scol + q) == srow) ? dval : 0.f;
      v[q] = x;
    }
    if (adv){
      uint2 ad = adv[(ri * 2 + ci) * 4 + g];
      v[0] += 1.5f * bf2f((u16)ad.x);
      v[1] += 1.5f * bf2f((u16)(ad.x >> 16));
      v[2] += 1.5f * bf2f((u16)ad.y);
      v[3] += 1.5f * bf2f((u16)(ad.y >> 16));
    }
    *(uint2*)nsAddr(D, srow, scol) = make_uint2(pk2(v[0], v[1]), pk2(v[2], v[3]));
  }
}

// =====================================================================
// K_prep: zero logits + convert w_dr -> bf16 pre-swizzled per-chunk LDS image
// =====================================================================
__global__ __launch_bounds__(256) void k_prep(const float* __restrict__ wdr,
                                              float* __restrict__ logits,
                                              u16* __restrict__ prep){
  int i = blockIdx.x * 256 + threadIdx.x;   // grid 256 -> 65536 threads
  if (i < 16384) logits[i] = 0.f;
  #pragma unroll
  for (int j = 0; j < 2; ++j){
    int e = i + j * 65536;
    int chunk = e >> 13, rem = e & 8191, d = rem >> 6, cb2 = rem & 63;
    int c = ((cb2 * 2) ^ ((d & 7) << 4)) >> 1;
    prep[e] = f2bf(wdr[d * 1024 + chunk * 64 + c]);
  }
}

// =====================================================================
// K1: 1x1 conv GEMM + BN1 + ReLU, center over d, scale 1/sqrt(128),
//     write W [b][hw][d] and WT [b][d][hw] (bf16)
// =====================================================================
__global__ __launch_bounds__(512) void k_conv(
    const u16* __restrict__ wprep, const float* __restrict__ x, const float* __restrict__ bdr,
    const float* __restrict__ g1, const float* __restrict__ be1,
    const float* __restrict__ m1, const float* __restrict__ v1,
    u16* __restrict__ Wg, u16* __restrict__ WTg){
  __shared__ union {
    struct { u16 A[4][8192]; u16 Bt[2][2048]; } s;   // 72KB -> 2 blocks/CU
    struct { float y[128 * 33]; float musum[512]; float mu[32]; } e;
  } sm;
  int t = threadIdx.x;
  int b = blockIdx.x >> 3, hw0 = (blockIdx.x & 7) * 32;
  const float* xb = x + (size_t)b * 262144 + hw0;

  int w = t >> 6, l = t & 63;
  int d0 = (w >> 1) * 32, hh = (w & 1) * 16;
  int lc = l & 15, lr = (l >> 4) * 4;

  const f4 fz = {0.f, 0.f, 0.f, 0.f};
  f4 acc[2]; acc[0] = fz; acc[1] = fz;

  int cp = t >> 5, hwl = t & 31;
  int bo0 = (4 * cp) ^ ((hwl & 7) << 4);
  int bo1 = (4 * cp + 64) ^ ((hwl & 7) << 4);

  float br[3][4];
  #pragma unroll
  for (int j = 0; j < 3; ++j){
    glds16(wprep + j * 8192 + t * 8,        sm.s.A[j] + t * 8);
    glds16(wprep + j * 8192 + 4096 + t * 8, sm.s.A[j] + 4096 + t * 8);
    __builtin_amdgcn_sched_barrier(0);
    int c0 = j * 64;
    br[j][0] = xb[(size_t)(c0 + 2 * cp)      * 256 + hwl];
    br[j][1] = xb[(size_t)(c0 + 2 * cp + 1)  * 256 + hwl];
    br[j][2] = xb[(size_t)(c0 + 2 * cp + 32) * 256 + hwl];
    br[j][3] = xb[(size_t)(c0 + 2 * cp + 33) * 256 + hwl];
    __builtin_amdgcn_sched_barrier(0);
  }

  #pragma unroll
  for (int k = 0; k < 16; ++k){
    if (k <= 12){
      const u16* src = wprep + (k + 3) * 8192;
      glds16(src + t * 8,        sm.s.A[(k + 3) & 3] + t * 8);
      glds16(src + 4096 + t * 8, sm.s.A[(k + 3) & 3] + 4096 + t * 8);
    }
    __builtin_amdgcn_sched_barrier(0);
    if (k <= 12)      asm volatile("s_waitcnt vmcnt(14)" ::: "memory");
    else if (k == 13) asm volatile("s_waitcnt vmcnt(12)" ::: "memory");
    else if (k == 14) asm volatile("s_waitcnt vmcnt(6)" ::: "memory");
    else              asm volatile("s_waitcnt vmcnt(0)" ::: "memory");
    __builtin_amdgcn_sched_barrier(0);
    *(u32*)((char*)sm.s.Bt[k & 1] + hwl * 128 + bo0) = pk2(br[k % 3][0], br[k % 3][1]);
    *(u32*)((char*)sm.s.Bt[k & 1] + hwl * 128 + bo1) = pk2(br[k % 3][2], br[k % 3][3]);
    __builtin_amdgcn_sched_barrier(0);
    if (k <= 12){
      int c0 = (k + 3) * 64;
      br[k % 3][0] = xb[(size_t)(c0 + 2 * cp)      * 256 + hwl];
      br[k % 3][1] = xb[(size_t)(c0 + 2 * cp + 1)  * 256 + hwl];
      br[k % 3][2] = xb[(size_t)(c0 + 2 * cp + 32) * 256 + hwl];
      br[k % 3][3] = xb[(size_t)(c0 + 2 * cp + 33) * 256 + hwl];
    }
    __builtin_amdgcn_sched_barrier(0);
    asm volatile("s_waitcnt lgkmcnt(0)" ::: "memory");
    __builtin_amdgcn_sched_barrier(0);
    __builtin_amdgcn_s_barrier();
    __builtin_amdgcn_sched_barrier(0);
    #pragma unroll
    for (int ks = 0; ks < 2; ++ks){
      int k0 = ks * 32;
      bf8 a0 = ldsFrag((const char*)sm.s.A[k & 3], d0,      k0, 128);
      bf8 a1 = ldsFrag((const char*)sm.s.A[k & 3], d0 + 16, k0, 128);
      bf8 b0 = ldsFrag((const char*)sm.s.Bt[k & 1], hh, k0, 128);
      acc[0] = MFMA(a0, b0, acc[0]);
      acc[1] = MFMA(a1, b0, acc[1]);
    }
    __builtin_amdgcn_sched_barrier(0);
    __builtin_amdgcn_s_barrier();
    __builtin_amdgcn_sched_barrier(0);
  }
  __syncthreads();

  #pragma unroll
  for (int i = 0; i < 2; ++i)
    #pragma unroll
    for (int r = 0; r < 4; ++r){
      int d = d0 + i * 16 + lr + r;
      float s1 = g1[d] * rsqrtf(v1[d] + 1e-5f);
      float t1 = (bdr[d] - m1[d]) * s1 + be1[d];
      int hwp = hh + lc;
      sm.e.y[d * 33 + hwp] = fmaxf(acc[i][r] * s1 + t1, 0.f);
    }
  __syncthreads();
  { int part = t >> 5, col = t & 31;
    float s = 0.f;
    #pragma unroll
    for (int i2 = 0; i2 < 8; ++i2) s += sm.e.y[(part * 8 + i2) * 33 + col];
    sm.e.musum[part * 32 + col] = s;
  }
  __syncthreads();
  if (t < 32){
    float m = 0.f;
    #pragma unroll
    for (int p = 0; p < 16; ++p) m += sm.e.musum[p * 32 + t];
    sm.e.mu[t] = m * (1.0f / 128.0f);
  }
  __syncthreads();
  const float ISM = 0.08838834764831845f;   // 1/sqrt(128)
  { int hwp = t >> 4, dc = (t & 15) * 8;
    float muv = sm.e.mu[hwp];
    u32 q[4];
    #pragma unroll
    for (int jj = 0; jj < 4; ++jj){
      float a = (sm.e.y[(dc + 2 * jj)     * 33 + hwp] - muv) * ISM;
      float c = (sm.e.y[(dc + 2 * jj + 1) * 33 + hwp] - muv) * ISM;
      q[jj] = pk2(a, c);
    }
    *(uint4*)(Wg + ((size_t)(b * 256 + hw0 + hwp) * 128 + dc)) = make_uint4(q[0], q[1], q[2], q[3]);
  }
  { int d = t >> 2, hc = (t & 3) * 8;
    u32 q[4];
    #pragma unroll
    for (int jj = 0; jj < 4; ++jj){
      int h0 = hc + 2 * jj, h1 = hc + 2 * jj + 1;
      float a = (sm.e.y[d * 33 + h0] - sm.e.mu[h0]) * ISM;
      float c = (sm.e.y[d * 33 + h1] - sm.e.mu[h1]) * ISM;
      q[jj] = pk2(a, c);
    }
    *(uint4*)(WTg + ((size_t)(b * 128 + d) * 256 + hw0 + hc)) = make_uint4(q[0], q[1], q[2], q[3]);
  }
}

// =====================================================================
// K3: per-batch Gram + Newton-Schulz (3 passes/iter, G register-resident,
//     32x32x16 MFMA, 64x64 tiles, b64 epilogues; pass2 split across 8 waves)
// =====================================================================
extern __shared__ char smns[];
__global__ __launch_bounds__(512, 2) void k_ns(const u16* __restrict__ WT,
                                               u16* __restrict__ yf, float* __restrict__ normAg){
  int b = blockIdx.x, t = threadIdx.x;
  char* Yb = smns;
  char* Zb = smns + 32768;
  char* T1 = smns + 65536;
  char* T2 = smns + 98304;
  char* T3 = smns + 131072;
  char* WTl = smns + 65536;
  char* G   = T3;
  float* trp = (float*)smns;

  int w = t >> 6, l = t & 63;
  int wq = w & 3;
  int R0 = (wq >> 1) * 64, C0 = (wq & 1) * 64;

  { const u16* src = WT + (size_t)b * 32768;
    int row = t >> 2, q = t & 3;
    #pragma unroll
    for (int j = 0; j < 8; ++j) {
      int c16 = q + j * 4;
      bf8 v = *(const bf8*)(src + row * 256 + c16 * 8);
      int ph = c16 ^ (row & 15);
      *(bf8*)(WTl + row * 512 + ph * 16) = v;
    }
  }
  if (t == 0) *trp = 0.f;
  __syncthreads();

  int R0g = (w & 3) * 32, C0g = (w >> 2) * 64;
  const f16f fz16 = {};
  f16f gac[2]; gac[0] = fz16; gac[1] = fz16;
  #pragma unroll
  for (int ks = 0; ks < 16; ++ks){
    bf8 a  = fragWT(WTl, R0g,      ks, l);
    bf8 b0 = fragWT(WTl, C0g,      ks, l);
    bf8 b1 = fragWT(WTl, C0g + 32, ks, l);
    gac[0] = MFMA32(a, b0, gac[0]);
    gac[1] = MFMA32(a, b1, gac[1]);
  }
  float tp = 0.f;
  #pragma unroll
  for (int ci = 0; ci < 2; ++ci)
    #pragma unroll
    for (int e = 0; e < 16; ++e){
      int row = R0g + (e & 3) + 8 * (e >> 2) + ((l >> 5) << 2);
      int col = C0g + ci * 32 + (l & 31);
      if (row == col) tp += gac[ci][e];
    }
  #pragma unroll
  for (int off = 32; off > 0; off >>= 1) tp += __shfl_down(tp, off);
  if (l == 0) atomicAdd(trp, tp);
  __syncthreads();

  float normA = fmaxf(*trp / 3.0f, 1e-12f);
  if (t == 0) normAg[b] = normA;
  float inv = 1.0f / normA;
  #pragma unroll
  for (int ci = 0; ci < 2; ++ci)
    #pragma unroll
    for (int g = 0; g < 4; ++g){
      int srow = C0g + ci * 32 + (l & 31);
      int scol = R0g + g * 8 + ((l >> 5) << 2);
      float v0 = gac[ci][g * 4 + 0] * inv, v1 = gac[ci][g * 4 + 1] * inv;
      float v2 = gac[ci][g * 4 + 2] * inv, v3 = gac[ci][g * 4 + 3] * inv;
      *(uint2*)nsAddr(G, srow, scol) = make_uint2(pk2(v0, v1), pk2(v2, v3));
    }
  __syncthreads();

  bf8 gA[8], gB[8];
  #pragma unroll
  for (int ks = 0; ks < 8; ++ks){
    gA[ks] = fragNS(G, C0,      ks, l);
    gB[ks] = fragNS(G, C0 + 32, ks, l);
  }
  { int row = t >> 2, q4 = t & 3;
    #pragma unroll
    for (int j = 0; j < 4; ++j){
      int c16 = q4 * 4 + j;
      int ph = c16 ^ (row & 15);
      bf8 gg = *(const bf8*)(G + row * 256 + ph * 16);
      bf8 yv, zv;
      #pragma unroll
      for (int e = 0; e < 8; ++e){
        int col = c16 * 8 + e;
        float y = -0.5f * bf2f((u16)gg[e]) + ((col == row) ? 1.5f : 0.f);
        yv[e] = (short)f2bf(y);
        zv[e] = (col == row) ? (short)f2bf(-0.5f) : (short)0;
      }
      *(bf8*)(Yb + row * 256 + ph * 16) = yv;
      *(bf8*)(Zb + row * 256 + ph * 16) = zv;
    }
  }
  __syncthreads();

  float z0 = 1.5f;
  for (int it = 0; it < 4; ++it){
    {
      f16f acc[2][2]; acc[0][0] = fz16; acc[0][1] = fz16; acc[1][0] = fz16; acc[1][1] = fz16;
      const char* As = (w < 4) ? Zb : Yb;
      #pragma unroll
      for (int ks = 0; ks < 8; ++ks){
        bf8 a0 = fragNS(As, R0,      ks, l);
        bf8 a1 = fragNS(As, R0 + 32, ks, l);
        acc[0][0] = MFMA32(a0, gA[ks], acc[0][0]); acc[0][1] = MFMA32(a0, gB[ks], acc[0][1]);
        acc[1][0] = MFMA32(a1, gA[ks], acc[1][0]); acc[1][1] = MFMA32(a1, gB[ks], acc[1][1]);
      }
      writeTile((w < 4) ? T1 : T3, acc, R0, C0, l, 1.0f, (w < 4) ? z0 : 0.f, nullptr);
    }
    __syncthreads();

    uint2 adv[16];
    {
      const char* addsrc = (w < 4) ? Zb : Yb;
      #pragma unroll
      for (int ri = 0; ri < 2; ++ri)
      #pragma unroll
      for (int ci = 0; ci < 2; ++ci)
      #pragma unroll
      for (int g = 0; g < 4; ++g){
        int srow = C0 + ci * 32 + (l & 31);
        int scol = R0 + ri * 32 + g * 8 + ((l >> 5) << 2);
        adv[(ri * 2 + ci) * 4 + g] = *(const uint2*)nsAddr((char*)addsrc, srow, scol);
      }
      int hC0 = C0 + ((w >> 2) << 5);           // 32-col half per wave
      f16f a2[2]; a2[0] = fz16; a2[1] = fz16;
      #pragma unroll
      for (int ks = 0; ks < 8; ++ks){
        bf8 a0 = fragNS(T1, R0,      ks, l);
        bf8 a1 = fragNS(T1, R0 + 32, ks, l);
        bf8 b0 = fragNS(Yb, hC0,     ks, l);
        a2[0] = MFMA32(a0, b0, a2[0]);
        a2[1] = MFMA32(a1, b0, a2[1]);
      }
      #pragma unroll
      for (int ri = 0; ri < 2; ++ri)
      #pragma unroll
      for (int g = 0; g < 4; ++g){
        int srow = hC0 + (l & 31);
        int scol = R0 + ri * 32 + g * 8 + ((l >> 5) << 2);
        float v0 = -0.5f * a2[ri][g * 4 + 0], v1 = -0.5f * a2[ri][g * 4 + 1];
        float v2 = -0.5f * a2[ri][g * 4 + 2], v3 = -0.5f * a2[ri][g * 4 + 3];
        *(uint2*)nsAddr(T2, srow, scol) = make_uint2(pk2(v0, v1), pk2(v2, v3));
      }
    }
    __syncthreads();

    if ((w >= 4) || (it < 3)){
      f16f acc[2][2]; acc[0][0] = fz16; acc[0][1] = fz16; acc[1][0] = fz16; acc[1][1] = fz16;
      const char* A3 = (w < 4) ? T2 : T3;
      const char* B3 = (w < 4) ? T1 : T2;
      mmPass(A3, B3, acc, R0, C0, l);
      writeTile((w < 4) ? Zb : Yb, acc, R0, C0, l, 1.0f, 0.f, adv);
    }
    __syncthreads();
    z0 *= 1.5f;
  }

  { int row = t >> 2, q = t & 3;
    u16* dst = yf + (size_t)b * 16384 + row * 128;
    #pragma unroll
    for (int j = 0; j < 4; ++j) {
      int c16 = q * 4 + j;
      int ph = c16 ^ (row & 15);
      *(bf8*)(dst + c16 * 8) = *(const bf8*)(Yb + row * 256 + ph * 16);
    }
  }
}

// =====================================================================
// K4: S = W @ yf @ W^T / sqrt(normA), then BN2 row-affine + rc -> s_post bf16
// =====================================================================
extern __shared__ char smex[];
__global__ __launch_bounds__(512) void k_expand(
    const u16* __restrict__ Wg, const u16* __restrict__ yf, const float* __restrict__ normAg,
    const float* __restrict__ g2, const float* __restrict__ be2, const float* __restrict__ m2,
    const float* __restrict__ v2, const float* __restrict__ rcw, const float* __restrict__ rcb,
    u16* __restrict__ sp){
  int blk = blockIdx.x, b = blk >> 2, iband = blk & 3;
  char* Bm = smex;
  char* Yl = smex + 65536;
  char* El = smex + 98304;
  int t = threadIdx.x;
  { const u16* src = Wg + (size_t)b * 32768;
    int row = t >> 1, q = t & 1;
    #pragma unroll
    for (int j = 0; j < 8; ++j) {
      int c16 = q + j * 2;
      bf8 v = *(const bf8*)(src + row * 128 + c16 * 8);
      int ph = c16 ^ (row & 7);
      *(bf8*)(Bm + row * 256 + ph * 16) = v;
    } }
  { const u16* src = yf + (size_t)b * 16384;
    int row = t >> 2, q = t & 3;
    #pragma unroll
    for (int j = 0; j < 4; ++j) {
      int c16 = q + j * 4;
      bf8 v = *(const bf8*)(src + row * 128 + c16 * 8);
      int ph = c16 ^ (row & 7);
      *(bf8*)(Yl + row * 256 + ph * 16) = v;
    } }
  __syncthreads();
  int w = t >> 6, l = t & 63, lc = l & 15, lr = (l >> 4) * 4;
  const f4 fz = {0.f, 0.f, 0.f, 0.f};
  { int r0 = (w >> 2) * 32, c0 = (w & 3) * 32;
    f4 acc[2][2];
    acc[0][0] = fz; acc[0][1] = fz; acc[1][0] = fz; acc[1][1] = fz;
    #pragma unroll
    for (int kk = 0; kk < 4; ++kk) {
      int k0 = kk * 32;
      bf8 a0 = ldsFrag(Bm, iband * 64 + r0,      k0, 256);
      bf8 a1 = ldsFrag(Bm, iband * 64 + r0 + 16, k0, 256);
      bf8 b0 = ldsFrag(Yl, c0,      k0, 256);
      bf8 b1 = ldsFrag(Yl, c0 + 16, k0, 256);
      acc[0][0] = MFMA(a0, b0, acc[0][0]); acc[0][1] = MFMA(a0, b1, acc[0][1]);
      acc[1][0] = MFMA(a1, b0, acc[1][0]); acc[1][1] = MFMA(a1, b1, acc[1][1]);
    }
    #pragma unroll
    for (int i = 0; i < 2; ++i)
      #pragma unroll
      for (int j = 0; j < 2; ++j)
        #pragma unroll
        for (int r = 0; r < 4; ++r)
          ldsPut(El, r0 + i * 16 + lr + r, c0 + j * 16 + lc, 256, f2bf(acc[i][j][r]));
  }
  __syncthreads();
  { float invs = rsqrtf(normAg[b]);
    int r0 = (w >> 2) * 32, c0 = (w & 3) * 64;
    f4 acc[2][4];
    #pragma unroll
    for (int i = 0; i < 2; ++i)
      #pragma unroll
      for (int j = 0; j < 4; ++j) acc[i][j] = fz;
    #pragma unroll
    for (int kk = 0; kk < 4; ++kk) {
      int k0 = kk * 32;
      bf8 a0 = ldsFrag(El, r0,      k0, 256);
      bf8 a1 = ldsFrag(El, r0 + 16, k0, 256);
      bf8 b0 = ldsFrag(Bm, c0,      k0, 256);
      bf8 b1 = ldsFrag(Bm, c0 + 16, k0, 256);
      bf8 b2 = ldsFrag(Bm, c0 + 32, k0, 256);
      bf8 b3 = ldsFrag(Bm, c0 + 48, k0, 256);
      acc[0][0] = MFMA(a0, b0, acc[0][0]); acc[0][1] = MFMA(a0, b1, acc[0][1]);
      acc[0][2] = MFMA(a0, b2, acc[0][2]); acc[0][3] = MFMA(a0, b3, acc[0][3]);
      acc[1][0] = MFMA(a1, b0, acc[1][0]); acc[1][1] = MFMA(a1, b1, acc[1][1]);
      acc[1][2] = MFMA(a1, b2, acc[1][2]); acc[1][3] = MFMA(a1, b3, acc[1][3]);
    }
    #pragma unroll
    for (int i = 0; i < 2; ++i)
      #pragma unroll
      for (int r = 0; r < 4; ++r) {
        int il = r0 + i * 16 + lr + r;
        int ig = iband * 64 + il;
        float bs = g2[ig] * rsqrtf(v2[ig] + 1e-5f);
        float al = bs * rcw[ig];
        float be = (be2[ig] - m2[ig] * bs) * rcw[ig] + rcb[ig];
        #pragma unroll
        for (int j = 0; j < 4; ++j) {
          int jg = c0 + j * 16 + lc;
          sp[(size_t)b * 65536 + ig * 256 + jg] = f2bf(acc[i][j][r] * invs * al + be);
        }
      }
  }
}

// =====================================================================
// K5: sequential-slab split-K GEMM.
// grid 1024 = 64 kslabs (K=1024) x 16 rgroups (16 fcw rows).
// Each block streams its 16 fcw rows SEQUENTIALLY (8 chunks x 512B per row).
// LDS 20KB single-buffered -> 8 blocks/CU. sp chunk LDS-staged (coalesced).
// Per wave: output rows 16w..16w+16 (batch) x 16 cols (fcw rows), acc = 1 f4.
// =====================================================================
__global__ __launch_bounds__(256) void k_fc(const u16* __restrict__ sp,
                                            const float* __restrict__ fcw,
                                            float4* __restrict__ partial4){
  __shared__ char Asp[16384];  // [64][256B] swz: sp chunk (64 rows x 128 bf16)
  __shared__ char Bf[4096];    // [16][256B] swz: fcw chunk (16 rows x 128 bf16)
  int rg = blockIdx.x & 15, kslab = blockIdx.x >> 4;
  int t = threadIdx.x, w = t >> 6, l = t & 63;
  int kbase = kslab * 1024;

  const f4 fz = {0.f, 0.f, 0.f, 0.f};
  f4 acc = fz;

  int frow = t >> 4, fc4 = t & 15;                 // fcw stage: 16 thr/row
  const float* fsrc = fcw + (size_t)(rg * 16 + frow) * 65536 + kbase;
  int arow = t >> 2, aq = t & 3;                   // sp stage: 4 thr/row
  const u16* asrc = sp + (size_t)arow * 65536 + kbase;

  for (int c = 0; c < 8; ++c){
    int k0 = c * 128;
    // fcw 16x128 f32 -> bf16 LDS (coalesced 512B runs per row, sequential in c)
    float4 v0 = *(const float4*)(fsrc + k0 + fc4 * 4);
    float4 v1 = *(const float4*)(fsrc + k0 + (fc4 + 16) * 4);
    // sp 64x128 bf16 -> LDS (coalesced 64B runs per row)
    bf8 av[4];
    #pragma unroll
    for (int j = 0; j < 4; ++j)
      av[j] = *(const bf8*)(asrc + k0 + (aq * 4 + j) * 8);
    {
      int o0 = frow * 256 + (((fc4 >> 1) ^ (frow & 7)) << 4) + ((fc4 & 1) << 3);
      *(uint2*)(Bf + o0) = make_uint2(pk2(v0.x, v0.y), pk2(v0.z, v0.w));
      int c4b = fc4 + 16;
      int o1 = frow * 256 + (((c4b >> 1) ^ (frow & 7)) << 4) + ((c4b & 1) << 3);
      *(uint2*)(Bf + o1) = make_uint2(pk2(v1.x, v1.y), pk2(v1.z, v1.w));
      #pragma unroll
      for (int j = 0; j < 4; ++j){
        int c16 = aq * 4 + j;
        *(bf8*)(Asp + arow * 256 + ((c16 ^ (arow & 7)) << 4)) = av[j];
      }
    }
    __syncthreads();
    #pragma unroll
    for (int ks = 0; ks < 4; ++ks){
      bf8 a = ldsFrag(Asp, w * 16, ks * 32, 256);
      bf8 b = ldsFrag(Bf, 0, ks * 32, 256);
      acc = MFMA(a, b, acc);
    }
    __syncthreads();
  }
  // fragment-linear store: 256 float4 per block, contiguous
  partial4[(size_t)(kslab * 16 + rg) * 256 + t] = make_float4(acc[0], acc[1], acc[2], acc[3]);
}

// =====================================================================
// K6: logits = sum over 64 kslabs + inverse fragment-permutation scatter
// 16 blocks (one per rg) x 256 thr; partial 4MB, L2-hot.
// =====================================================================
__global__ __launch_bounds__(256) void k_red(const float4* __restrict__ partial4,
                                             float* __restrict__ logits){
  int rg = blockIdx.x;
  int t = threadIdx.x;
  float4 a = {0,0,0,0};
  #pragma unroll 8
  for (int ks = 0; ks < 64; ++ks){
    float4 v = partial4[(size_t)(ks * 16 + rg) * 256 + t];
    a.x += v.x; a.y += v.y; a.z += v.z; a.w += v.w;
  }
  int w = t >> 6, l = t & 63;
  int brow0 = w * 16 + ((l >> 4) << 2);
  int rcol = rg * 16 + (l & 15);
  float* dst = logits + brow0 * 256 + rcol;
  dst[0]   = a.x;
  dst[256] = a.y;
  dst[512] = a.z;
  dst[768] = a.w;
}

// =====================================================================
// K7: out = x * sigmoid(logits + fc_b)
// =====================================================================
__global__ __launch_bounds__(256) void k_mul(const float* __restrict__ x,
                                             const float* __restrict__ logits,
                                             const float* __restrict__ fcb,
                                             float* __restrict__ out, int n4){
  int i = blockIdx.x * 256 + threadIdx.x;
  int str = gridDim.x * 256;
  for (; i < n4; i += str) {
    int e = i << 2;
    int b = e >> 18;
    int hw = e & 255;
    float4 xv = ((const float4*)x)[i];
    float4 lg = *(const float4*)(logits + (b << 8) + hw);
    float4 fb = *(const float4*)(fcb + hw);
    float4 o;
    o.x = xv.x / (1.f + expf(-(lg.x + fb.x)));
    o.y = xv.y / (1.f + expf(-(lg.y + fb.y)));
    o.z = xv.z / (1.f + expf(-(lg.z + fb.z)));
    o.w = xv.w / (1.f + expf(-(lg.w + fb.w)));
    ((float4*)out)[i] = o;
  }
}

// =====================================================================
extern "C" void kernel_launch(void* const* d_in, const int* in_sizes, int n_in,
                              void* d_out, int out_size, void* d_ws, size_t ws_size,
                              hipStream_t stream){
  const float* x   = (const float*)d_in[0];
  const float* wdr = (const float*)d_in[1];
  const float* bdr = (const float*)d_in[2];
  const float* g1  = (const float*)d_in[3];
  const float* be1 = (const float*)d_in[4];
  const float* m1  = (const float*)d_in[5];
  const float* v1  = (const float*)d_in[6];
  const float* g2  = (const float*)d_in[7];
  const float* be2 = (const float*)d_in[8];
  const float* m2  = (const float*)d_in[9];
  const float* v2  = (const float*)d_in[10];
  const float* rcw = (const float*)d_in[11];
  const float* rcb = (const float*)d_in[12];
  const float* fcw = (const float*)d_in[13];
  const float* fcb = (const float*)d_in[14];
  float* out = (float*)d_out;
  char* ws = (char*)d_ws;
  u16*    Wg  = (u16*)(ws);                          // 4 MB
  u16*    WTg = (u16*)(ws + (4u  << 20));            // 4 MB
  u16*    yfg = (u16*)(ws + (8u  << 20));            // 2 MB
  float*  nAg = (float*)(ws + (10u << 20));          // 256 B
  u16*    wpr = (u16*)(ws + (10u << 20) + 4096);     // 256 KB
  u16*    spg = (u16*)(ws + (11u << 20));            // 8 MB
  float*  lgt = (float*)(ws + (20u << 20));          // 64 KB
  float4* prt = (float4*)(ws + (24u << 20));         // 4 MB [64*16][256] f4

  hipFuncSetAttribute((const void*)k_ns,     hipFuncAttributeMaxDynamicSharedMemorySize, 163840);
  hipFuncSetAttribute((const void*)k_expand, hipFuncAttributeMaxDynamicSharedMemorySize, 114688);

  k_prep  <<<256,  256, 0,      stream>>>(wdr, lgt, wpr);
  k_conv  <<<512,  512, 0,      stream>>>(wpr, x, bdr, g1, be1, m1, v1, Wg, WTg);
  k_ns    <<<64,   512, 163840, stream>>>(WTg, yfg, nAg);
  k_expand<<<256,  512, 114688, stream>>>(Wg, yfg, nAg, g2, be2, m2, v2, rcw, rcb, spg);
  k_fc    <<<1024, 256, 0,      stream>>>(spg, fcw, prt);
  k_red   <<<16,   256, 0,      stream>>>(prt, lgt);
  k_mul   <<<2048, 256, 0,      stream>>>(x, lgt, fcb, out, 4194304);
}